// Round 2
// baseline (419.402 us; speedup 1.0000x reference)
//
#include <hip/hip_runtime.h>
#include <type_traits>

// Problem constants: H=16, D=64, DM=1024, L=256, B=64, CHUNK=64, SCALE=1/8.

typedef short v8s __attribute__((ext_vector_type(8)));
typedef float v4f __attribute__((ext_vector_type(4)));

__device__ __forceinline__ float bf2f(short s) {
    unsigned int u = ((unsigned int)(unsigned short)s) << 16;
    float f;
    __builtin_memcpy(&f, &u, 4);
    return f;
}
__device__ __forceinline__ short f2bf(float f) {
    unsigned int u;
    __builtin_memcpy(&u, &f, 4);
    u = u + 0x7fffu + ((u >> 16) & 1u);   // RNE
    return (short)(u >> 16);
}

// async global->LDS, 16B per lane; LDS dest = wave-uniform base + lane*16
__device__ __forceinline__ void load_lds16(const short* g, short* l) {
    __builtin_amdgcn_global_load_lds((const __attribute__((address_space(1))) void*)g,
                                     (__attribute__((address_space(3))) void*)l, 16, 0, 0);
}

// ---------------- fp32 -> bf16 conversion (vectorized x4) ----------------
__global__ void __launch_bounds__(256)
cvt_bf16(const float* __restrict__ in, short* __restrict__ out, int n4) {
    int i = blockIdx.x * 256 + threadIdx.x;
    if (i >= n4) return;
    float4 v = ((const float4*)in)[i];
    short4 o;
    o.x = f2bf(v.x); o.y = f2bf(v.y); o.z = f2bf(v.z); o.w = f2bf(v.w);
    ((short4*)out)[i] = o;
}

// ---------------- bf16 MFMA GEMM:  C[M,N] = A[M,K] * B[N,K]^T ----------------
// 256x256 tile, BK=64, 8 waves (2Mx4N), 512 threads. 8-phase schedule.
// R2 change vs R1: fragment ds_reads are issued INSIDE the previous phase's
// MFMA region (before/after the cluster), so their latency hides under MFMA;
// compiler emits counted lgkmcnt waits from register deps. Stage issue points
// and the vmcnt(4) schedule are IDENTICAL to the verified R1 version.
// A-frags reload late (after MFMA, sched_barrier-pinned) to stay in 124 VGPR.
template <typename OutT>
__global__ void __launch_bounds__(512, 2)
gemm_nt(const short* __restrict__ Ap, const short* __restrict__ Bp,
        OutT* __restrict__ C, int M, int N, int K) {
    // [buf][mat(0=A,1=B)][256 rows][64 cols]
    __shared__ __align__(16) short lds[2][2][256 * 64];

    const int tid = threadIdx.x;
    const int w = tid >> 6, lane = tid & 63;
    const int wm = w >> 2, wn = w & 3;          // wave tile: 128 rows x 64 cols
    const int lq = lane >> 4, lr = lane & 15;
    const int asw = (lr & 7) * 8;               // read-side XOR swizzle (shorts)
    const int rr = tid >> 3;                    // staging: row within 64-row chunk
    const int scol = ((tid & 7) * 8) ^ ((rr & 7) * 8);  // pre-swizzled source col

    // XCD-aware bijective block swizzle (nwg % 8 == 0 for our launches)
    int bid = blockIdx.y * gridDim.x + blockIdx.x;
    int nwg = gridDim.x * gridDim.y;
    int swz = (bid & 7) * (nwg >> 3) + (bid >> 3);
    int bm = swz % gridDim.x, bn = swz / gridDim.x;

    v4f acc[8][4] = {};
    v8s a[4][2];        // A frags for current qm (4 m-frags x 2 k-halves)
    v8s b[2][2][2];     // B frags for both qn (qn x 2 n-frags x 2 k-halves)

    const int NT = K >> 6;          // K-tiles of 64
    const int nIter = NT >> 1;      // 2 K-tiles per iteration

#define BAR_() do { asm volatile("" ::: "memory"); __builtin_amdgcn_s_barrier(); asm volatile("" ::: "memory"); } while (0)
#define SBAR_() __builtin_amdgcn_sched_barrier(0)
#define VMCNT4_() asm volatile("s_waitcnt vmcnt(4)" ::: "memory")
    // stage one half-tile (128 rows x 64 cols) = 2 x global_load_lds(16B) per thread
#define STAGE_(MAT, BUF, HALF, KT) do { \
        const short* g_ = ((MAT) ? Bp : Ap) + \
            (long)(((MAT) ? bn : bm) * 256 + (HALF) * 128 + rr) * K + (KT) * 64 + scol; \
        short* l_ = &lds[BUF][MAT][(HALF) * 8192] + w * 512; \
        load_lds16(g_, l_); \
        load_lds16(g_ + (long)64 * K, l_ + 4096); \
    } while (0)
    // A fragment loads for quadrant QM from buffer BUF (8 x ds_read_b128)
#define LDA_(QM, BUF) do { \
        _Pragma("unroll") \
        for (int mi = 0; mi < 4; ++mi) { \
            const short* pa_ = &lds[BUF][0][(wm * 128 + (QM) * 64 + mi * 16 + lr) * 64]; \
            a[mi][0] = *(const v8s*)&pa_[(lq * 8) ^ asw]; \
            a[mi][1] = *(const v8s*)&pa_[(32 + lq * 8) ^ asw]; \
        } \
    } while (0)
    // B fragment loads for quadrant QN from buffer BUF (4 x ds_read_b128)
#define LDB_(QN, BUF) do { \
        _Pragma("unroll") \
        for (int ni = 0; ni < 2; ++ni) { \
            const short* pb_ = &lds[BUF][1][(wn * 64 + (QN) * 32 + ni * 16 + lr) * 64]; \
            b[QN][ni][0] = *(const v8s*)&pb_[(lq * 8) ^ asw]; \
            b[QN][ni][1] = *(const v8s*)&pb_[(32 + lq * 8) ^ asw]; \
        } \
    } while (0)
    // one C-quadrant x K=64: 16 MFMA, prioritized
#define MFMA_(QM, QN) do { \
        __builtin_amdgcn_s_setprio(1); \
        _Pragma("unroll") \
        for (int kk = 0; kk < 2; ++kk) \
            _Pragma("unroll") \
            for (int mi = 0; mi < 4; ++mi) \
                _Pragma("unroll") \
                for (int ni = 0; ni < 2; ++ni) \
                    acc[(QM) * 4 + mi][(QN) * 2 + ni] = __builtin_amdgcn_mfma_f32_16x16x32_bf16( \
                        a[mi][kk], b[QN][ni][kk], acc[(QM) * 4 + mi][(QN) * 2 + ni], 0, 0, 0); \
        __builtin_amdgcn_s_setprio(0); \
    } while (0)

    // ---- prologue: tile0 (all 4 half-tiles) into buf0, tile1.B into buf1 ----
    STAGE_(1, 0, 0, 0);
    STAGE_(1, 0, 1, 0);
    STAGE_(0, 0, 0, 0);
    STAGE_(0, 0, 1, 0);
    STAGE_(1, 1, 0, 1);
    STAGE_(1, 1, 1, 1);
    VMCNT4_();          // tile0's 8 loads landed; tile1.B (4) stays in flight
    BAR_();

    // ---- main loop: 8 regions per iteration, 2 K-tiles ----
    // vmcnt trace (steady state, entering R0): outstanding = [prevR6, prevR7] (buf1.B)
    for (int it = 0; it < nIter; ++it) {
        const int t1 = 2 * it + 1;
        int t2 = 2 * it + 2; if (t2 >= NT) t2 -= NT;  // wrapped tail staging keeps
        int t3 = 2 * it + 3; if (t3 >= NT) t3 -= NT;  // vmcnt counts exact (data unused)

        // R0: load all frags for phases 0,1 (b1 hides under MFMA); compute (0,0)
        LDA_(0, 0); LDB_(0, 0); LDB_(1, 0);
        STAGE_(0, 1, 0, t1);
        MFMA_(0, 0);
        SBAR_(); BAR_();
        // R1: compute (0,1) (all frags resident); reload A qm=1 AFTER the cluster
        STAGE_(0, 1, 1, t1);
        MFMA_(0, 1);
        SBAR_();
        LDA_(1, 0);
        SBAR_(); BAR_();
        // R2: compute (1,0) (a issued late in R1 -> short wait)
        STAGE_(1, 0, 0, t2);
        MFMA_(1, 0);
        SBAR_(); BAR_();
        // R3: compute (1,1); counted wait completes buf1 (A from R0/R1, B from prev R6/R7)
        STAGE_(1, 0, 1, t2);
        VMCNT4_();
        MFMA_(1, 1);
        SBAR_(); BAR_();
        // R4: buf1 = tile t1
        LDA_(0, 1); LDB_(0, 1); LDB_(1, 1);
        STAGE_(0, 0, 0, t2);
        MFMA_(0, 0);
        SBAR_(); BAR_();
        // R5
        STAGE_(0, 0, 1, t2);
        MFMA_(0, 1);
        SBAR_();
        LDA_(1, 1);
        SBAR_(); BAR_();
        // R6
        STAGE_(1, 1, 0, t3);
        MFMA_(1, 0);
        SBAR_(); BAR_();
        // R7: counted wait completes buf0 (tile t2) for next iteration's R0
        STAGE_(1, 1, 1, t3);
        VMCNT4_();
        MFMA_(1, 1);
        SBAR_(); BAR_();
    }

#undef BAR_
#undef SBAR_
#undef VMCNT4_
#undef STAGE_
#undef LDA_
#undef LDB_
#undef MFMA_

    // ---- epilogue ----
#pragma unroll
    for (int m = 0; m < 8; ++m)
#pragma unroll
        for (int n = 0; n < 4; ++n)
#pragma unroll
            for (int r = 0; r < 4; ++r) {
                int row = bm * 256 + wm * 128 + m * 16 + lq * 4 + r;
                int col = bn * 256 + wn * 64 + n * 16 + lr;
                float v = acc[m][n][r];
                if constexpr (std::is_same_v<OutT, short>)
                    C[(long)row * N + col] = f2bf(v);
                else
                    C[(long)row * N + col] = v;
            }
}

// ---------------- fast-weight scan (MFMA bf16), BOTH memories per block ----------------
// Fuses mem=0 and mem=1 (shared q,v staging) and the pi0 mixture epilogue:
// writes lmix = SCALE*(p*o1 + (1-p)*o2) in bf16 directly. Eliminates the
// separate mix kernel and the l1/l2 round-trip.
#define SW(row, s) ((row) * 72 + ((((s) >> 3) ^ (((row) >> 4) & 7)) << 3) + ((s) & 7))

__device__ __forceinline__ void phi_store(const short* __restrict__ g,
                                          short* sS, short* sT, int r, int seg) {
    union { int4 v[2]; short s[16]; } u;
    u.v[0] = *(const int4*)(g);
    u.v[1] = *(const int4*)(g + 8);
    float f[16]; float ssum = 0.f;
#pragma unroll
    for (int i = 0; i < 16; i++) {
        float x = bf2f(u.s[i]);
        float e = x > 0.f ? x + 1.f : __expf(x);
        f[i] = e; ssum += e;
    }
    ssum += __shfl_xor(ssum, 1, 64);
    ssum += __shfl_xor(ssum, 2, 64);
    float inv = 1.f / ssum;
    union { int4 v[2]; short s[16]; } o;
#pragma unroll
    for (int i = 0; i < 16; i++) o.s[i] = f2bf(f[i] * inv);
    *(int4*)&sS[SW(r, seg)] = o.v[0];
    *(int4*)&sS[SW(r, seg + 8)] = o.v[1];
    if (sT) {
#pragma unroll
        for (int i = 0; i < 16; i++) sT[SW(seg + i, r)] = o.s[i];
    }
}

__global__ void __launch_bounds__(256)
fastweight(const short* __restrict__ qkv, const float* __restrict__ pi0,
           short* __restrict__ outm) {
    const int bid = blockIdx.x;
    const int h = bid & 15, b = bid >> 4;
    const int tid = threadIdx.x;
    const int w = tid >> 6, lane = tid & 63;
    const int lq = lane >> 4, lr = lane & 15;
    __shared__ __align__(16) short sq[64 * 72];
    __shared__ __align__(16) short sk1S[64 * 72];   // k1 rows, then S1 overwrites
    __shared__ __align__(16) short sk2S[64 * 72];   // k2 rows, then S2 overwrites
    __shared__ __align__(16) short sk1T[64 * 72];
    __shared__ __align__(16) short sk2T[64 * 72];
    __shared__ __align__(16) short svT[64 * 72];
    __shared__ __align__(16) short sW1T[64 * 72];
    __shared__ __align__(16) short sW2T[64 * 72];
    __shared__ float spi[256];

    for (int i = tid; i < 64 * 36; i += 256) { ((int*)sW1T)[i] = 0; ((int*)sW2T)[i] = 0; }
    spi[tid] = pi0[h * 256 + tid];

    const int r = tid >> 2, seg = (tid & 3) * 16;

    v4f wacc1[4] = {}, wacc2[4] = {};   // persistent W^T slices

    for (int c = 0; c < 4; c++) {
        __syncthreads();
        const long gbase = ((long)((c * 64 + r) * 64 + b)) * 4096 + h * 256;
        phi_store(qkv + gbase + seg, sq, nullptr, r, seg);           // q
        phi_store(qkv + gbase + 64 + seg, sk1S, sk1T, r, seg);       // k1
        phi_store(qkv + gbase + 128 + seg, sk2S, sk2T, r, seg);      // k2
        {   // v: transposed only
            union { int4 v[2]; short s[16]; } u;
            u.v[0] = *(const int4*)(qkv + gbase + 192 + seg);
            u.v[1] = *(const int4*)(qkv + gbase + 192 + seg + 8);
#pragma unroll
            for (int i = 0; i < 16; i++) svT[SW(seg + i, r)] = u.s[i];
        }
        __syncthreads();

        v8s qa0 = *(const v8s*)&sq[SW(16 * w + lr, lq * 8)];
        v8s qa1 = *(const v8s*)&sq[SW(16 * w + lr, 32 + lq * 8)];

        // ---- S1 = q k1^T, S2 = q k2^T (independent chains) ----
        v4f sacc1[4], sacc2[4];
#pragma unroll
        for (int n = 0; n < 4; n++) {
            v8s b10 = *(const v8s*)&sk1S[SW(16 * n + lr, lq * 8)];
            v8s b11 = *(const v8s*)&sk1S[SW(16 * n + lr, 32 + lq * 8)];
            v8s b20 = *(const v8s*)&sk2S[SW(16 * n + lr, lq * 8)];
            v8s b21 = *(const v8s*)&sk2S[SW(16 * n + lr, 32 + lq * 8)];
            v4f t1 = {}, t2 = {};
            t1 = __builtin_amdgcn_mfma_f32_16x16x32_bf16(qa0, b10, t1, 0, 0, 0);
            t2 = __builtin_amdgcn_mfma_f32_16x16x32_bf16(qa0, b20, t2, 0, 0, 0);
            t1 = __builtin_amdgcn_mfma_f32_16x16x32_bf16(qa1, b11, t1, 0, 0, 0);
            t2 = __builtin_amdgcn_mfma_f32_16x16x32_bf16(qa1, b21, t2, 0, 0, 0);
            sacc1[n] = t1; sacc2[n] = t2;
        }
        __syncthreads();
#pragma unroll
        for (int n = 0; n < 4; n++)
#pragma unroll
            for (int rr = 0; rr < 4; rr++) {
                int t_ = 16 * w + lq * 4 + rr;
                int s_ = 16 * n + lr;
                sk1S[SW(t_, s_)] = f2bf(s_ <= t_ ? sacc1[n][rr] : 0.f);
                sk2S[SW(t_, s_)] = f2bf(s_ <= t_ ? sacc2[n][rr] : 0.f);
            }

        // ---- O1 = S1 v + q W1, O2 = S2 v + q W2 ----
        v8s sa10 = *(const v8s*)&sk1S[SW(16 * w + lr, lq * 8)];
        v8s sa11 = *(const v8s*)&sk1S[SW(16 * w + lr, 32 + lq * 8)];
        v8s sa20 = *(const v8s*)&sk2S[SW(16 * w + lr, lq * 8)];
        v8s sa21 = *(const v8s*)&sk2S[SW(16 * w + lr, 32 + lq * 8)];
        v4f o1[4], o2[4];
#pragma unroll
        for (int n = 0; n < 4; n++) {
            v8s vb0 = *(const v8s*)&svT[SW(16 * n + lr, lq * 8)];
            v8s vb1 = *(const v8s*)&svT[SW(16 * n + lr, 32 + lq * 8)];
            v8s wb10 = *(const v8s*)&sW1T[SW(16 * n + lr, lq * 8)];
            v8s wb11 = *(const v8s*)&sW1T[SW(16 * n + lr, 32 + lq * 8)];
            v8s wb20 = *(const v8s*)&sW2T[SW(16 * n + lr, lq * 8)];
            v8s wb21 = *(const v8s*)&sW2T[SW(16 * n + lr, 32 + lq * 8)];
            v4f t1 = {}, t2 = {};
            t1 = __builtin_amdgcn_mfma_f32_16x16x32_bf16(sa10, vb0, t1, 0, 0, 0);
            t2 = __builtin_amdgcn_mfma_f32_16x16x32_bf16(sa20, vb0, t2, 0, 0, 0);
            t1 = __builtin_amdgcn_mfma_f32_16x16x32_bf16(sa11, vb1, t1, 0, 0, 0);
            t2 = __builtin_amdgcn_mfma_f32_16x16x32_bf16(sa21, vb1, t2, 0, 0, 0);
            t1 = __builtin_amdgcn_mfma_f32_16x16x32_bf16(qa0, wb10, t1, 0, 0, 0);
            t2 = __builtin_amdgcn_mfma_f32_16x16x32_bf16(qa0, wb20, t2, 0, 0, 0);
            t1 = __builtin_amdgcn_mfma_f32_16x16x32_bf16(qa1, wb11, t1, 0, 0, 0);
            t2 = __builtin_amdgcn_mfma_f32_16x16x32_bf16(qa1, wb21, t2, 0, 0, 0);
            o1[n] = t1; o2[n] = t2;
        }
        // ---- pi0 mixture + SCALE, write bf16 ----
#pragma unroll
        for (int n = 0; n < 4; n++)
#pragma unroll
            for (int rr = 0; rr < 4; rr++) {
                int t_ = 16 * w + lq * 4 + rr;
                int l = c * 64 + t_;
                float p = fminf(fmaxf(spi[l], 0.f), 1.f);
                float val = 0.125f * (p * o1[n][rr] + (1.f - p) * o2[n][rr]);
                long o = ((long)(l * 64 + b)) * 1024 + h * 64 + 16 * n + lr;
                outm[o] = f2bf(val);
            }

        if (c < 3) {
            __syncthreads();
            // ---- W1^T += v^T k1, W2^T += v^T k2 ----
            v8s va0 = *(const v8s*)&svT[SW(16 * w + lr, lq * 8)];
            v8s va1 = *(const v8s*)&svT[SW(16 * w + lr, 32 + lq * 8)];
#pragma unroll
            for (int n = 0; n < 4; n++) {
                v8s kb10 = *(const v8s*)&sk1T[SW(16 * n + lr, lq * 8)];
                v8s kb11 = *(const v8s*)&sk1T[SW(16 * n + lr, 32 + lq * 8)];
                v8s kb20 = *(const v8s*)&sk2T[SW(16 * n + lr, lq * 8)];
                v8s kb21 = *(const v8s*)&sk2T[SW(16 * n + lr, 32 + lq * 8)];
                wacc1[n] = __builtin_amdgcn_mfma_f32_16x16x32_bf16(va0, kb10, wacc1[n], 0, 0, 0);
                wacc2[n] = __builtin_amdgcn_mfma_f32_16x16x32_bf16(va0, kb20, wacc2[n], 0, 0, 0);
                wacc1[n] = __builtin_amdgcn_mfma_f32_16x16x32_bf16(va1, kb11, wacc1[n], 0, 0, 0);
                wacc2[n] = __builtin_amdgcn_mfma_f32_16x16x32_bf16(va1, kb21, wacc2[n], 0, 0, 0);
            }
#pragma unroll
            for (int n = 0; n < 4; n++)
#pragma unroll
                for (int rr = 0; rr < 4; rr++) {
                    sW1T[SW(16 * w + lq * 4 + rr, 16 * n + lr)] = f2bf(wacc1[n][rr]);
                    sW2T[SW(16 * w + lq * 4 + rr, 16 * n + lr)] = f2bf(wacc2[n][rr]);
                }
        }
    }
}

// ---------------- residual + LayerNorm over DM=1024 ----------------
__global__ void __launch_bounds__(256)
ln_kernel(const float* __restrict__ h, const float* __restrict__ attn,
          const float* __restrict__ gamma, const float* __restrict__ beta,
          float* __restrict__ out) {
    const int row = blockIdx.x;
    const long base = (long)row * 1024;
    const int tid = threadIdx.x;
    float4 xh = ((const float4*)(h + base))[tid];
    float4 xa = ((const float4*)(attn + base))[tid];
    float4 x;
    x.x = xh.x + xa.x; x.y = xh.y + xa.y; x.z = xh.z + xa.z; x.w = xh.w + xa.w;
    float s = x.x + x.y + x.z + x.w;
    float s2 = x.x * x.x + x.y * x.y + x.z * x.z + x.w * x.w;
#pragma unroll
    for (int m = 32; m > 0; m >>= 1) {
        s += __shfl_xor(s, m, 64);
        s2 += __shfl_xor(s2, m, 64);
    }
    __shared__ float ps[4], ps2[4];
    int w = tid >> 6, lane = tid & 63;
    if (lane == 0) { ps[w] = s; ps2[w] = s2; }
    __syncthreads();
    s = ps[0] + ps[1] + ps[2] + ps[3];
    s2 = ps2[0] + ps2[1] + ps2[2] + ps2[3];
    float mu = s * (1.f / 1024.f);
    float var = s2 * (1.f / 1024.f) - mu * mu;
    float inv = rsqrtf(var + 1e-5f);
    float4 g = ((const float4*)gamma)[tid];
    float4 bb = ((const float4*)beta)[tid];
    float4 o;
    o.x = (x.x - mu) * inv * g.x + bb.x;
    o.y = (x.y - mu) * inv * g.y + bb.y;
    o.z = (x.z - mu) * inv * g.z + bb.z;
    o.w = (x.w - mu) * inv * g.w + bb.w;
    ((float4*)(out + base))[tid] = o;
}

extern "C" void kernel_launch(void* const* d_in, const int* in_sizes, int n_in,
                              void* d_out, int out_size, void* d_ws, size_t ws_size,
                              hipStream_t stream) {
    const float* h     = (const float*)d_in[0];
    const float* qkvw  = (const float*)d_in[1];
    const float* ow    = (const float*)d_in[2];
    const float* gamma = (const float*)d_in[3];
    const float* beta  = (const float*)d_in[4];
    const float* pi0   = (const float*)d_in[5];
    float* out = (float*)d_out;
    char* ws = (char*)d_ws;

    short* h_bf   = (short*)(ws);                 // 32MB; reused later as lmix
    short* wq_bf  = (short*)(ws + 33554432);      // 8MB
    short* wo_bf  = (short*)(ws + 41943040);      // 2MB
    short* qkv_bf = (short*)(ws + 44040192);      // 128MB; reused later as attn f32 (64MB)
    float* attnf  = (float*)(ws + 44040192);
    short* lmix   = h_bf;

    cvt_bf16<<<16384, 256, 0, stream>>>(h, h_bf, 16777216 / 4);
    cvt_bf16<<<4096, 256, 0, stream>>>(qkvw, wq_bf, 4194304 / 4);
    cvt_bf16<<<1024, 256, 0, stream>>>(ow, wo_bf, 1048576 / 4);

    gemm_nt<short><<<dim3(64, 16), 512, 0, stream>>>(h_bf, wq_bf, qkv_bf, 16384, 4096, 1024);

    fastweight<<<1024, 256, 0, stream>>>(qkv_bf, pi0, lmix);

    gemm_nt<float><<<dim3(64, 4), 512, 0, stream>>>(lmix, wo_bf, attnf, 16384, 1024, 1024);

    ln_kernel<<<16384, 256, 0, stream>>>(h, attnf, gamma, beta, out);
}

// Round 3
// 405.759 us; speedup vs baseline: 1.0336x; 1.0336x over previous
//
#include <hip/hip_runtime.h>
#include <type_traits>

// Problem constants: H=16, D=64, DM=1024, L=256, B=64, CHUNK=64, SCALE=1/8.

typedef short v8s __attribute__((ext_vector_type(8)));
typedef float v4f __attribute__((ext_vector_type(4)));

__device__ __forceinline__ float bf2f(short s) {
    unsigned int u = ((unsigned int)(unsigned short)s) << 16;
    float f;
    __builtin_memcpy(&f, &u, 4);
    return f;
}
__device__ __forceinline__ short f2bf(float f) {
    unsigned int u;
    __builtin_memcpy(&u, &f, 4);
    u = u + 0x7fffu + ((u >> 16) & 1u);   // RNE
    return (short)(u >> 16);
}

// async global->LDS, 16B per lane; LDS dest = wave-uniform base + lane*16
__device__ __forceinline__ void load_lds16(const short* g, short* l) {
    __builtin_amdgcn_global_load_lds((const __attribute__((address_space(1))) void*)g,
                                     (__attribute__((address_space(3))) void*)l, 16, 0, 0);
}

// ---------------- fp32 -> bf16 conversion (vectorized x4) ----------------
__global__ void __launch_bounds__(256)
cvt_bf16(const float* __restrict__ in, short* __restrict__ out, int n4) {
    int i = blockIdx.x * 256 + threadIdx.x;
    if (i >= n4) return;
    float4 v = ((const float4*)in)[i];
    short4 o;
    o.x = f2bf(v.x); o.y = f2bf(v.y); o.z = f2bf(v.z); o.w = f2bf(v.w);
    ((short4*)out)[i] = o;
}

// ---------------- bf16 MFMA GEMM:  C[M,N] = A[M,K] * B[N,K]^T ----------------
// 256x256 tile, BK=64, 8 waves (2Mx4N), 512 threads, 8-phase counted-vmcnt
// schedule (verified R1/R2). R3 change: L2-compact per-XCD block mapping —
// each XCD owns an 8-row bm chunk (4MB A panel, fits its 4MB L2) and walks
// bn with the A chunk hot. Requires gridDim.x == 64 (true for both launches).
template <typename OutT>
__global__ void __launch_bounds__(512, 2)
gemm_nt(const short* __restrict__ Ap, const short* __restrict__ Bp,
        OutT* __restrict__ C, int M, int N, int K) {
    // [buf][mat(0=A,1=B)][256 rows][64 cols]
    __shared__ __align__(16) short lds[2][2][256 * 64];

    const int tid = threadIdx.x;
    const int w = tid >> 6, lane = tid & 63;
    const int wm = w >> 2, wn = w & 3;          // wave tile: 128 rows x 64 cols
    const int lq = lane >> 4, lr = lane & 15;
    const int asw = (lr & 7) * 8;               // read-side XOR swizzle (shorts)
    const int rr = tid >> 3;                    // staging: row within 64-row chunk
    const int scol = ((tid & 7) * 8) ^ ((rr & 7) * 8);  // pre-swizzled source col

    // L2-compact bijective XCD mapping (bm chunk of 8 per XCD)
    int bid = blockIdx.y * gridDim.x + blockIdx.x;
    int bm, bn;
    if (gridDim.x == 64) {
        int xcd = bid & 7, u = bid >> 3;
        bm = xcd * 8 + (u & 7);
        bn = u >> 3;
    } else {
        int nwg = gridDim.x * gridDim.y;
        int swz = (bid & 7) * (nwg >> 3) + (bid >> 3);
        bm = swz % gridDim.x; bn = swz / gridDim.x;
    }

    v4f acc[8][4] = {};
    v8s a[4][2];        // A frags for current qm (4 m-frags x 2 k-halves)
    v8s b[2][2][2];     // B frags for both qn (qn x 2 n-frags x 2 k-halves)

    const int NT = K >> 6;          // K-tiles of 64
    const int nIter = NT >> 1;      // 2 K-tiles per iteration

#define BAR_() do { asm volatile("" ::: "memory"); __builtin_amdgcn_s_barrier(); asm volatile("" ::: "memory"); } while (0)
#define SBAR_() __builtin_amdgcn_sched_barrier(0)
#define VMCNT4_() asm volatile("s_waitcnt vmcnt(4)" ::: "memory")
    // stage one half-tile (128 rows x 64 cols) = 2 x global_load_lds(16B) per thread
#define STAGE_(MAT, BUF, HALF, KT) do { \
        const short* g_ = ((MAT) ? Bp : Ap) + \
            (long)(((MAT) ? bn : bm) * 256 + (HALF) * 128 + rr) * K + (KT) * 64 + scol; \
        short* l_ = &lds[BUF][MAT][(HALF) * 8192] + w * 512; \
        load_lds16(g_, l_); \
        load_lds16(g_ + (long)64 * K, l_ + 4096); \
    } while (0)
    // A fragment loads for quadrant QM from buffer BUF (8 x ds_read_b128)
#define LDA_(QM, BUF) do { \
        _Pragma("unroll") \
        for (int mi = 0; mi < 4; ++mi) { \
            const short* pa_ = &lds[BUF][0][(wm * 128 + (QM) * 64 + mi * 16 + lr) * 64]; \
            a[mi][0] = *(const v8s*)&pa_[(lq * 8) ^ asw]; \
            a[mi][1] = *(const v8s*)&pa_[(32 + lq * 8) ^ asw]; \
        } \
    } while (0)
    // B fragment loads for quadrant QN from buffer BUF (4 x ds_read_b128)
#define LDB_(QN, BUF) do { \
        _Pragma("unroll") \
        for (int ni = 0; ni < 2; ++ni) { \
            const short* pb_ = &lds[BUF][1][(wn * 64 + (QN) * 32 + ni * 16 + lr) * 64]; \
            b[QN][ni][0] = *(const v8s*)&pb_[(lq * 8) ^ asw]; \
            b[QN][ni][1] = *(const v8s*)&pb_[(32 + lq * 8) ^ asw]; \
        } \
    } while (0)
    // one C-quadrant x K=64: 16 MFMA, prioritized
#define MFMA_(QM, QN) do { \
        __builtin_amdgcn_s_setprio(1); \
        _Pragma("unroll") \
        for (int kk = 0; kk < 2; ++kk) \
            _Pragma("unroll") \
            for (int mi = 0; mi < 4; ++mi) \
                _Pragma("unroll") \
                for (int ni = 0; ni < 2; ++ni) \
                    acc[(QM) * 4 + mi][(QN) * 2 + ni] = __builtin_amdgcn_mfma_f32_16x16x32_bf16( \
                        a[mi][kk], b[QN][ni][kk], acc[(QM) * 4 + mi][(QN) * 2 + ni], 0, 0, 0); \
        __builtin_amdgcn_s_setprio(0); \
    } while (0)

    // ---- prologue: tile0 (all 4 half-tiles) into buf0, tile1.B into buf1 ----
    STAGE_(1, 0, 0, 0);
    STAGE_(1, 0, 1, 0);
    STAGE_(0, 0, 0, 0);
    STAGE_(0, 0, 1, 0);
    STAGE_(1, 1, 0, 1);
    STAGE_(1, 1, 1, 1);
    VMCNT4_();          // tile0's 8 loads landed; tile1.B (4) stays in flight
    BAR_();

    // ---- main loop: 8 regions per iteration, 2 K-tiles ----
    for (int it = 0; it < nIter; ++it) {
        const int t1 = 2 * it + 1;
        int t2 = 2 * it + 2; if (t2 >= NT) t2 -= NT;  // wrapped tail staging keeps
        int t3 = 2 * it + 3; if (t3 >= NT) t3 -= NT;  // vmcnt counts exact (data unused)

        // R0: load all frags for phases 0,1 (b1 hides under MFMA); compute (0,0)
        LDA_(0, 0); LDB_(0, 0); LDB_(1, 0);
        STAGE_(0, 1, 0, t1);
        MFMA_(0, 0);
        SBAR_(); BAR_();
        // R1: compute (0,1) (all frags resident); reload A qm=1 AFTER the cluster
        STAGE_(0, 1, 1, t1);
        MFMA_(0, 1);
        SBAR_();
        LDA_(1, 0);
        SBAR_(); BAR_();
        // R2: compute (1,0) (a issued late in R1 -> short wait)
        STAGE_(1, 0, 0, t2);
        MFMA_(1, 0);
        SBAR_(); BAR_();
        // R3: compute (1,1); counted wait completes buf1 (A from R0/R1, B from prev R6/R7)
        STAGE_(1, 0, 1, t2);
        VMCNT4_();
        MFMA_(1, 1);
        SBAR_(); BAR_();
        // R4: buf1 = tile t1
        LDA_(0, 1); LDB_(0, 1); LDB_(1, 1);
        STAGE_(0, 0, 0, t2);
        MFMA_(0, 0);
        SBAR_(); BAR_();
        // R5
        STAGE_(0, 0, 1, t2);
        MFMA_(0, 1);
        SBAR_();
        LDA_(1, 1);
        SBAR_(); BAR_();
        // R6
        STAGE_(1, 1, 0, t3);
        MFMA_(1, 0);
        SBAR_(); BAR_();
        // R7: counted wait completes buf0 (tile t2) for next iteration's R0
        STAGE_(1, 1, 1, t3);
        VMCNT4_();
        MFMA_(1, 1);
        SBAR_(); BAR_();
    }

#undef BAR_
#undef SBAR_
#undef VMCNT4_
#undef STAGE_
#undef LDA_
#undef LDB_
#undef MFMA_

    // ---- epilogue ----
#pragma unroll
    for (int m = 0; m < 8; ++m)
#pragma unroll
        for (int n = 0; n < 4; ++n)
#pragma unroll
            for (int r = 0; r < 4; ++r) {
                int row = bm * 256 + wm * 128 + m * 16 + lq * 4 + r;
                int col = bn * 256 + wn * 64 + n * 16 + lr;
                float v = acc[m][n][r];
                if constexpr (std::is_same_v<OutT, short>)
                    C[(long)row * N + col] = f2bf(v);
                else
                    C[(long)row * N + col] = v;
            }
}

// ---------------- fast-weight scan (MFMA bf16), BOTH memories per block ----------------
// R3: stride-64 + XOR swizzle LDS (65KB -> 2 blocks/CU instead of 148KB -> 1)
// and register prefetch of the next c-step's q/k1/k2/v (hides global latency
// under the MFMA phases). Swizzle spreads banks for BOTH b128 frag reads
// (row&7 term) and transposed scalar writes (row>>4 term).
#define SW(row, s) (((row) << 6) + ((s) ^ (((((row) >> 4) ^ (row)) & 7) << 3)))

union FW16 { int4 v[2]; short s[16]; };

__device__ __forceinline__ void phi_to_lds(const FW16& u, short* sS, short* sT,
                                           int r, int seg) {
    float f[16]; float ssum = 0.f;
#pragma unroll
    for (int i = 0; i < 16; i++) {
        float x = bf2f(u.s[i]);
        float e = x > 0.f ? x + 1.f : __expf(x);
        f[i] = e; ssum += e;
    }
    ssum += __shfl_xor(ssum, 1, 64);
    ssum += __shfl_xor(ssum, 2, 64);
    float inv = 1.f / ssum;
    FW16 o;
#pragma unroll
    for (int i = 0; i < 16; i++) o.s[i] = f2bf(f[i] * inv);
    *(int4*)&sS[SW(r, seg)] = o.v[0];
    *(int4*)&sS[SW(r, seg + 8)] = o.v[1];
    if (sT) {
#pragma unroll
        for (int i = 0; i < 16; i++) sT[SW(seg + i, r)] = o.s[i];
    }
}

__global__ void __launch_bounds__(256, 2)
fastweight(const short* __restrict__ qkv, const float* __restrict__ pi0,
           short* __restrict__ outm) {
    const int bid = blockIdx.x;
    const int h = bid & 15, b = bid >> 4;
    const int tid = threadIdx.x;
    const int w = tid >> 6, lane = tid & 63;
    const int lq = lane >> 4, lr = lane & 15;
    __shared__ __align__(16) short sq[64 * 64];
    __shared__ __align__(16) short sk1S[64 * 64];   // k1 rows, then S1 overwrites
    __shared__ __align__(16) short sk2S[64 * 64];   // k2 rows, then S2 overwrites
    __shared__ __align__(16) short sk1T[64 * 64];
    __shared__ __align__(16) short sk2T[64 * 64];
    __shared__ __align__(16) short svT[64 * 64];
    __shared__ __align__(16) short sW1T[64 * 64];
    __shared__ __align__(16) short sW2T[64 * 64];
    __shared__ float spi[256];

    for (int i = tid; i < 2048; i += 256) { ((int*)sW1T)[i] = 0; ((int*)sW2T)[i] = 0; }
    spi[tid] = pi0[h * 256 + tid];

    const int r = tid >> 2, seg = (tid & 3) * 16;

    v4f wacc1[4] = {}, wacc2[4] = {};   // persistent W^T slices

    // current c-step's raw qkv rows (prefetched)
    FW16 cq, ck1, ck2, cv;
    {
        const short* g = qkv + ((long)(r * 64 + b)) * 4096 + h * 256 + seg;
        cq.v[0]  = *(const int4*)(g);        cq.v[1]  = *(const int4*)(g + 8);
        ck1.v[0] = *(const int4*)(g + 64);   ck1.v[1] = *(const int4*)(g + 72);
        ck2.v[0] = *(const int4*)(g + 128);  ck2.v[1] = *(const int4*)(g + 136);
        cv.v[0]  = *(const int4*)(g + 192);  cv.v[1]  = *(const int4*)(g + 200);
    }

#pragma unroll
    for (int c = 0; c < 4; c++) {
        FW16 nq, nk1, nk2, nv;
        if (c < 3) {   // issue next c-step's loads; land during this c's MFMA
            const short* g = qkv + ((long)(((c + 1) * 64 + r) * 64 + b)) * 4096 + h * 256 + seg;
            nq.v[0]  = *(const int4*)(g);        nq.v[1]  = *(const int4*)(g + 8);
            nk1.v[0] = *(const int4*)(g + 64);   nk1.v[1] = *(const int4*)(g + 72);
            nk2.v[0] = *(const int4*)(g + 128);  nk2.v[1] = *(const int4*)(g + 136);
            nv.v[0]  = *(const int4*)(g + 192);  nv.v[1]  = *(const int4*)(g + 200);
        }
        __syncthreads();   // prev c's MFMA reads done; LDS reusable
        phi_to_lds(cq, sq, nullptr, r, seg);
        phi_to_lds(ck1, sk1S, sk1T, r, seg);
        phi_to_lds(ck2, sk2S, sk2T, r, seg);
#pragma unroll
        for (int i = 0; i < 16; i++) svT[SW(seg + i, r)] = cv.s[i];
        __syncthreads();

        v8s qa0 = *(const v8s*)&sq[SW(16 * w + lr, lq * 8)];
        v8s qa1 = *(const v8s*)&sq[SW(16 * w + lr, 32 + lq * 8)];

        // ---- S1 = q k1^T, S2 = q k2^T (independent chains) ----
        v4f sacc1[4], sacc2[4];
#pragma unroll
        for (int n = 0; n < 4; n++) {
            v8s b10 = *(const v8s*)&sk1S[SW(16 * n + lr, lq * 8)];
            v8s b11 = *(const v8s*)&sk1S[SW(16 * n + lr, 32 + lq * 8)];
            v8s b20 = *(const v8s*)&sk2S[SW(16 * n + lr, lq * 8)];
            v8s b21 = *(const v8s*)&sk2S[SW(16 * n + lr, 32 + lq * 8)];
            v4f t1 = {}, t2 = {};
            t1 = __builtin_amdgcn_mfma_f32_16x16x32_bf16(qa0, b10, t1, 0, 0, 0);
            t2 = __builtin_amdgcn_mfma_f32_16x16x32_bf16(qa0, b20, t2, 0, 0, 0);
            t1 = __builtin_amdgcn_mfma_f32_16x16x32_bf16(qa1, b11, t1, 0, 0, 0);
            t2 = __builtin_amdgcn_mfma_f32_16x16x32_bf16(qa1, b21, t2, 0, 0, 0);
            sacc1[n] = t1; sacc2[n] = t2;
        }
        __syncthreads();
#pragma unroll
        for (int n = 0; n < 4; n++)
#pragma unroll
            for (int rr = 0; rr < 4; rr++) {
                int t_ = 16 * w + lq * 4 + rr;
                int s_ = 16 * n + lr;
                sk1S[SW(t_, s_)] = f2bf(s_ <= t_ ? sacc1[n][rr] : 0.f);
                sk2S[SW(t_, s_)] = f2bf(s_ <= t_ ? sacc2[n][rr] : 0.f);
            }

        // ---- O1 = S1 v + q W1, O2 = S2 v + q W2 ----
        // (S rows 16w.. were written by this wave -> same-wave lgkm ordering)
        v8s sa10 = *(const v8s*)&sk1S[SW(16 * w + lr, lq * 8)];
        v8s sa11 = *(const v8s*)&sk1S[SW(16 * w + lr, 32 + lq * 8)];
        v8s sa20 = *(const v8s*)&sk2S[SW(16 * w + lr, lq * 8)];
        v8s sa21 = *(const v8s*)&sk2S[SW(16 * w + lr, 32 + lq * 8)];
        v4f o1[4], o2[4];
#pragma unroll
        for (int n = 0; n < 4; n++) {
            v8s vb0 = *(const v8s*)&svT[SW(16 * n + lr, lq * 8)];
            v8s vb1 = *(const v8s*)&svT[SW(16 * n + lr, 32 + lq * 8)];
            v8s wb10 = *(const v8s*)&sW1T[SW(16 * n + lr, lq * 8)];
            v8s wb11 = *(const v8s*)&sW1T[SW(16 * n + lr, 32 + lq * 8)];
            v8s wb20 = *(const v8s*)&sW2T[SW(16 * n + lr, lq * 8)];
            v8s wb21 = *(const v8s*)&sW2T[SW(16 * n + lr, 32 + lq * 8)];
            v4f t1 = {}, t2 = {};
            t1 = __builtin_amdgcn_mfma_f32_16x16x32_bf16(sa10, vb0, t1, 0, 0, 0);
            t2 = __builtin_amdgcn_mfma_f32_16x16x32_bf16(sa20, vb0, t2, 0, 0, 0);
            t1 = __builtin_amdgcn_mfma_f32_16x16x32_bf16(sa11, vb1, t1, 0, 0, 0);
            t2 = __builtin_amdgcn_mfma_f32_16x16x32_bf16(sa21, vb1, t2, 0, 0, 0);
            t1 = __builtin_amdgcn_mfma_f32_16x16x32_bf16(qa0, wb10, t1, 0, 0, 0);
            t2 = __builtin_amdgcn_mfma_f32_16x16x32_bf16(qa0, wb20, t2, 0, 0, 0);
            t1 = __builtin_amdgcn_mfma_f32_16x16x32_bf16(qa1, wb11, t1, 0, 0, 0);
            t2 = __builtin_amdgcn_mfma_f32_16x16x32_bf16(qa1, wb21, t2, 0, 0, 0);
            o1[n] = t1; o2[n] = t2;
        }
        // ---- pi0 mixture + SCALE, write bf16 ----
#pragma unroll
        for (int n = 0; n < 4; n++)
#pragma unroll
            for (int rr = 0; rr < 4; rr++) {
                int t_ = 16 * w + lq * 4 + rr;
                int l = c * 64 + t_;
                float p = fminf(fmaxf(spi[l], 0.f), 1.f);
                float val = 0.125f * (p * o1[n][rr] + (1.f - p) * o2[n][rr]);
                long o = ((long)(l * 64 + b)) * 1024 + h * 64 + 16 * n + lr;
                outm[o] = f2bf(val);
            }

        if (c < 3) {
            __syncthreads();
            // ---- W1^T += v^T k1, W2^T += v^T k2 ----
            v8s va0 = *(const v8s*)&svT[SW(16 * w + lr, lq * 8)];
            v8s va1 = *(const v8s*)&svT[SW(16 * w + lr, 32 + lq * 8)];
#pragma unroll
            for (int n = 0; n < 4; n++) {
                v8s kb10 = *(const v8s*)&sk1T[SW(16 * n + lr, lq * 8)];
                v8s kb11 = *(const v8s*)&sk1T[SW(16 * n + lr, 32 + lq * 8)];
                v8s kb20 = *(const v8s*)&sk2T[SW(16 * n + lr, lq * 8)];
                v8s kb21 = *(const v8s*)&sk2T[SW(16 * n + lr, 32 + lq * 8)];
                wacc1[n] = __builtin_amdgcn_mfma_f32_16x16x32_bf16(va0, kb10, wacc1[n], 0, 0, 0);
                wacc2[n] = __builtin_amdgcn_mfma_f32_16x16x32_bf16(va0, kb20, wacc2[n], 0, 0, 0);
                wacc1[n] = __builtin_amdgcn_mfma_f32_16x16x32_bf16(va1, kb11, wacc1[n], 0, 0, 0);
                wacc2[n] = __builtin_amdgcn_mfma_f32_16x16x32_bf16(va1, kb21, wacc2[n], 0, 0, 0);
            }
#pragma unroll
            for (int n = 0; n < 4; n++)
#pragma unroll
                for (int rr = 0; rr < 4; rr++) {
                    sW1T[SW(16 * w + lq * 4 + rr, 16 * n + lr)] = f2bf(wacc1[n][rr]);
                    sW2T[SW(16 * w + lq * 4 + rr, 16 * n + lr)] = f2bf(wacc2[n][rr]);
                }
        }
        cq = nq; ck1 = nk1; ck2 = nk2; cv = nv;
    }
}

// ---------------- residual + LayerNorm over DM=1024 ----------------
__global__ void __launch_bounds__(256)
ln_kernel(const float* __restrict__ h, const float* __restrict__ attn,
          const float* __restrict__ gamma, const float* __restrict__ beta,
          float* __restrict__ out) {
    const int row = blockIdx.x;
    const long base = (long)row * 1024;
    const int tid = threadIdx.x;
    float4 xh = ((const float4*)(h + base))[tid];
    float4 xa = ((const float4*)(attn + base))[tid];
    float4 x;
    x.x = xh.x + xa.x; x.y = xh.y + xa.y; x.z = xh.z + xa.z; x.w = xh.w + xa.w;
    float s = x.x + x.y + x.z + x.w;
    float s2 = x.x * x.x + x.y * x.y + x.z * x.z + x.w * x.w;
#pragma unroll
    for (int m = 32; m > 0; m >>= 1) {
        s += __shfl_xor(s, m, 64);
        s2 += __shfl_xor(s2, m, 64);
    }
    __shared__ float ps[4], ps2[4];
    int w = tid >> 6, lane = tid & 63;
    if (lane == 0) { ps[w] = s; ps2[w] = s2; }
    __syncthreads();
    s = ps[0] + ps[1] + ps[2] + ps[3];
    s2 = ps2[0] + ps2[1] + ps2[2] + ps2[3];
    float mu = s * (1.f / 1024.f);
    float var = s2 * (1.f / 1024.f) - mu * mu;
    float inv = rsqrtf(var + 1e-5f);
    float4 g = ((const float4*)gamma)[tid];
    float4 bb = ((const float4*)beta)[tid];
    float4 o;
    o.x = (x.x - mu) * inv * g.x + bb.x;
    o.y = (x.y - mu) * inv * g.y + bb.y;
    o.z = (x.z - mu) * inv * g.z + bb.z;
    o.w = (x.w - mu) * inv * g.w + bb.w;
    ((float4*)(out + base))[tid] = o;
}

extern "C" void kernel_launch(void* const* d_in, const int* in_sizes, int n_in,
                              void* d_out, int out_size, void* d_ws, size_t ws_size,
                              hipStream_t stream) {
    const float* h     = (const float*)d_in[0];
    const float* qkvw  = (const float*)d_in[1];
    const float* ow    = (const float*)d_in[2];
    const float* gamma = (const float*)d_in[3];
    const float* beta  = (const float*)d_in[4];
    const float* pi0   = (const float*)d_in[5];
    float* out = (float*)d_out;
    char* ws = (char*)d_ws;

    short* h_bf   = (short*)(ws);                 // 32MB; reused later as lmix
    short* wq_bf  = (short*)(ws + 33554432);      // 8MB
    short* wo_bf  = (short*)(ws + 41943040);      // 2MB
    short* qkv_bf = (short*)(ws + 44040192);      // 128MB; reused later as attn f32 (64MB)
    float* attnf  = (float*)(ws + 44040192);
    short* lmix   = h_bf;

    cvt_bf16<<<16384, 256, 0, stream>>>(h, h_bf, 16777216 / 4);
    cvt_bf16<<<4096, 256, 0, stream>>>(qkvw, wq_bf, 4194304 / 4);
    cvt_bf16<<<1024, 256, 0, stream>>>(ow, wo_bf, 1048576 / 4);

    gemm_nt<short><<<dim3(64, 16), 512, 0, stream>>>(h_bf, wq_bf, qkv_bf, 16384, 4096, 1024);

    fastweight<<<1024, 256, 0, stream>>>(qkv_bf, pi0, lmix);

    gemm_nt<float><<<dim3(64, 4), 512, 0, stream>>>(lmix, wo_bf, attnf, 16384, 1024, 1024);

    ln_kernel<<<16384, 256, 0, stream>>>(h, attnf, gamma, beta, out);
}